// Round 2
// baseline (5469.098 us; speedup 1.0000x reference)
//
#include <hip/hip_runtime.h>
#include <cstdint>
#include <cstddef>

#define NPTS 8192
#define NB 8
#define NS 2048
#define KG 32
#define NF 64
#define NROWS (NB*NS*KG)   // 524288

// Distance with NO fma contraction: bitwise-identical to numpy f32
// ((dx*dx + dy*dy) + dz*dz). -ffp-contract=fast-honor-pragmas honors this
// pragma; inlined ops carry no 'contract' flag so LLVM cannot fuse them.
__device__ __forceinline__ float dist2_exact(float ax, float ay, float az,
                                             float bx, float by, float bz)
{
#pragma clang fp contract(off)
  float dx = ax - bx;
  float dy = ay - by;
  float dz = az - bz;
  return dx * dx + dy * dy + dz * dz;
}

// ======================== FPS ========================
// One block per batch. 256 threads x 32 points/thread, coords+dmin in regs.
// Packed key (float bits <<32 | ~idx) -> max == argmax with first-index
// tiebreak, matching jnp.argmax/np.argmax first-occurrence semantics.
__launch_bounds__(256)
__global__ void fps_kernel(const float* __restrict__ xyz, float* __restrict__ cents)
{
  const int b = blockIdx.x;
  const int t = threadIdx.x;
  const float* base = xyz + (size_t)b * NPTS * 3;

  float px[32], py[32], pz[32], dmin[32];
#pragma unroll
  for (int j = 0; j < 32; ++j) {
    int i = j * 256 + t;
    px[j] = base[3*i+0];
    py[j] = base[3*i+1];
    pz[j] = base[3*i+2];
    dmin[j] = 1e10f;
  }

  __shared__ unsigned long long spk[2][4];
  __shared__ float sx[2][4], sy[2][4], sz[2][4];

  float cx = base[0], cy = base[1], cz = base[2];
  if (t == 0) {
    float* c0 = cents + (size_t)b * NS * 3;
    c0[0] = cx; c0[1] = cy; c0[2] = cz;
  }

  for (int it = 1; it < NS; ++it) {
    unsigned long long best = 0ull;
    float wx = 0.f, wy = 0.f, wz = 0.f;
#pragma unroll
    for (int j = 0; j < 32; ++j) {
      float d = dist2_exact(px[j], py[j], pz[j], cx, cy, cz);
      float m = fminf(dmin[j], d);
      dmin[j] = m;
      unsigned long long p = ((unsigned long long)__float_as_uint(m) << 32)
                           | (unsigned long long)(unsigned int)(~(unsigned)(j*256 + t));
      if (p > best) { best = p; wx = px[j]; wy = py[j]; wz = pz[j]; }
    }
    // wave butterfly reduce (coords ride along with the key; keys unique)
#pragma unroll
    for (int off = 32; off > 0; off >>= 1) {
      unsigned long long op = __shfl_xor(best, off, 64);
      float ox = __shfl_xor(wx, off, 64);
      float oy = __shfl_xor(wy, off, 64);
      float oz = __shfl_xor(wz, off, 64);
      if (op > best) { best = op; wx = ox; wy = oy; wz = oz; }
    }
    const int pb = it & 1;   // double-buffered partials -> single barrier/iter
    if ((t & 63) == 0) {
      int w = t >> 6;
      spk[pb][w] = best; sx[pb][w] = wx; sy[pb][w] = wy; sz[pb][w] = wz;
    }
    __syncthreads();
    unsigned long long bb = spk[pb][0];
    float bx = sx[pb][0], by = sy[pb][0], bz = sz[pb][0];
#pragma unroll
    for (int q = 1; q < 4; ++q) {
      unsigned long long oq = spk[pb][q];
      if (oq > bb) { bb = oq; bx = sx[pb][q]; by = sy[pb][q]; bz = sz[pb][q]; }
    }
    cx = bx; cy = by; cz = bz;        // next query point, known to all threads
    if (t == 0) {
      float* cp = cents + ((size_t)b * NS + it) * 3;
      cp[0] = bx; cp[1] = by; cp[2] = bz;
    }
  }
}

// ======================== Ball query ========================
// One wave per centroid. Scan points in index order, append first 32 inside
// radius (== ref's top_k of lowest indices), pad with first found index.
__launch_bounds__(256)
__global__ void ballq_kernel(const float* __restrict__ xyz,
                             const float* __restrict__ cents,
                             int* __restrict__ gidx)
{
  const int gid  = blockIdx.x * 256 + threadIdx.x;
  const int w    = gid >> 6;          // centroid id 0..16383
  const int lane = gid & 63;
  const int b    = w >> 11;
  const float* base = xyz + (size_t)b * NPTS * 3;
  const float cx = cents[3*w+0], cy = cents[3*w+1], cz = cents[3*w+2];
  const float R2 = (float)(0.2 * 0.2);
  int* out = gidx + (size_t)w * KG;

  int filled = 0, first = -1;
  for (int c = 0; c < NPTS/64; ++c) {
    int i = (c << 6) | lane;
    float d = dist2_exact(base[3*i+0], base[3*i+1], base[3*i+2], cx, cy, cz);
    bool inb = (d <= R2);
    unsigned long long mask = __ballot(inb);
    if (first < 0 && mask) first = (c << 6) + (__ffsll((long long)mask) - 1);
    int pre  = __popcll(mask & ((1ull << lane) - 1ull));
    int slot = filled + pre;
    if (inb && slot < KG) out[slot] = i;
    filled += __popcll(mask);
    if (filled >= KG) break;
  }
  // centroid is itself an input point => filled >= 1 => first is valid
  if (filled < KG && lane < KG && lane >= filled) out[lane] = first;
}

// ======================== MLP chain ========================
// Thread-per-row recompute chain. Layer outputs go to a 64KB LDS tile
// [channel][row-in-block] which is also the transpose buffer for stats.

template<int CIN, int COUT>
__device__ __forceinline__ void dense(const float* __restrict__ w,
                                      const float* __restrict__ bias,
                                      const float* xin, float* tile, int t)
{
  for (int o = 0; o < COUT; o += 4) {       // rolled: small I$, 4 indep chains
    float a0 = bias[o], a1 = bias[o+1], a2 = bias[o+2], a3 = bias[o+3];
#pragma unroll
    for (int c = 0; c < CIN; ++c) {
      float xv = xin[c];
      a0 = fmaf(w[(o+0)*CIN+c], xv, a0);
      a1 = fmaf(w[(o+1)*CIN+c], xv, a1);
      a2 = fmaf(w[(o+2)*CIN+c], xv, a2);
      a3 = fmaf(w[(o+3)*CIN+c], xv, a3);
    }
    tile[(o+0)*128 + t] = a0;
    tile[(o+1)*128 + t] = a1;
    tile[(o+2)*128 + t] = a2;
    tile[(o+3)*128 + t] = a3;
  }
}

template<int C>
__device__ __forceinline__ void readnorm(const float* tile, const float* __restrict__ a,
                                         const float* __restrict__ sh, float* xo, int t)
{
#pragma unroll
  for (int c = 0; c < C; ++c)
    xo[c] = fmaxf(fmaf(a[c], tile[c*128 + t], sh[c]), 0.f);
}

template<int C>
__device__ __forceinline__ void stats_acc(const float* tile, float* __restrict__ gs,
                                          int t, int blk)
{
  if (t >= C) return;
  float s1 = 0.f, s2 = 0.f;
#pragma unroll
  for (int r = 0; r < 128; ++r) {
    int rr = (r + t) & 127;                  // swizzle: conflict-free row read
    float v = tile[t*128 + rr];
    s1 += v;
    s2 = fmaf(v, v, s2);
  }
  int rep = blk & 7;                         // 8-way replicated accumulators
  atomicAdd(&gs[rep*C + t], s1);
  atomicAdd(&gs[8*C + rep*C + t], s2);
}

// MODE: 1/2/3 = stats pass for layer1/2/3, 4 = final (norm3+relu+maxpool)
template<int MODE>
__launch_bounds__(128)
__global__ void chain_kernel(const float* __restrict__ xyz,
                             const float* __restrict__ feats,
                             const float* __restrict__ cents,
                             const int* __restrict__ gidx,
                             const float* __restrict__ w0, const float* __restrict__ b0,
                             const float* __restrict__ w1, const float* __restrict__ b1,
                             const float* __restrict__ w2, const float* __restrict__ b2,
                             const float* __restrict__ prm,   // a0,sh0,a1,sh1 (64 each), a2,sh2 (128 each)
                             float* __restrict__ stats,
                             float* __restrict__ outp)
{
  __shared__ float tile[128*128];            // 64 KB
  const int t = threadIdx.x;
  const int r = blockIdx.x * 128 + t;
  const int b = r >> 16;                     // 65536 rows per batch
  const int cs = r >> 5;
  const int i = gidx[r];

  const float* pp = xyz + ((size_t)(b << 13) + i) * 3;
  const float* cc = cents + (size_t)cs * 3;

  float xin[67];
  xin[0] = pp[0] - cc[0];
  xin[1] = pp[1] - cc[1];
  xin[2] = pp[2] - cc[2];
  const float4* f4 = (const float4*)(feats + (((size_t)(b << 13) + i) << 6));
#pragma unroll
  for (int q = 0; q < 16; ++q) {
    float4 v = f4[q];
    xin[3+4*q+0] = v.x; xin[3+4*q+1] = v.y; xin[3+4*q+2] = v.z; xin[3+4*q+3] = v.w;
  }

  dense<67,64>(w0, b0, xin, tile, t);
  __syncthreads();
  if (MODE == 1) { stats_acc<64>(tile, stats + 0, t, blockIdx.x); return; }

  float xm[64];
  readnorm<64>(tile, prm + 0, prm + 64, xm, t);
  __syncthreads();
  dense<64,64>(w1, b1, xm, tile, t);
  __syncthreads();
  if (MODE == 2) { stats_acc<64>(tile, stats + 1024, t, blockIdx.x); return; }

  readnorm<64>(tile, prm + 128, prm + 192, xm, t);
  __syncthreads();
  dense<64,128>(w2, b2, xm, tile, t);
  __syncthreads();
  if (MODE == 3) { stats_acc<128>(tile, stats + 2048, t, blockIdx.x); return; }

  // final: norm3 + relu + max over k (32 consecutive rows); 4 groups per block
  const float* a2 = prm + 256;
  const float* sh2 = prm + 384;
  const int cs0 = blockIdx.x * 4;
  const float av = a2[t], sv = sh2[t];
#pragma unroll
  for (int p = 0; p < 4; ++p) {
    float m = 0.f;                            // relu => max >= 0
#pragma unroll
    for (int k = 0; k < 32; ++k) {
      int kk = (k + t) & 31;                  // conflict-free swizzle
      float v = tile[t*128 + p*32 + kk];
      m = fmaxf(m, fmaf(av, v, sv));
    }
    outp[(size_t)(cs0 + p) * 128 + t] = m;
  }
}

__global__ void finalize_kernel(const float* __restrict__ stats,
                                const float* __restrict__ g,
                                const float* __restrict__ beta,
                                float* __restrict__ pa, float* __restrict__ psh, int C)
{
  int c = threadIdx.x;
  if (c >= C) return;
  float s1 = 0.f, s2 = 0.f;
  for (int rr = 0; rr < 8; ++rr) { s1 += stats[rr*C + c]; s2 += stats[8*C + rr*C + c]; }
  const float invn = 1.0f / (float)NROWS;
  float mean = s1 * invn;
  float var  = s2 * invn - mean * mean;
  float rs   = 1.0f / sqrtf(var + 1e-5f);
  float a    = g[c] * rs;
  pa[c]  = a;
  psh[c] = fmaf(-mean, a, beta[c]);
}

__global__ void zero_kernel(float* __restrict__ p, int n)
{
  int i = blockIdx.x * 256 + threadIdx.x;
  if (i < n) p[i] = 0.f;
}

// ======================== launch ========================
extern "C" void kernel_launch(void* const* d_in, const int* in_sizes, int n_in,
                              void* d_out, int out_size, void* d_ws, size_t ws_size,
                              hipStream_t stream)
{
  (void)in_sizes; (void)n_in; (void)out_size; (void)ws_size;
  const float* xyz   = (const float*)d_in[0];
  const float* feats = (const float*)d_in[1];
  const float* w0 = (const float*)d_in[2],  *b0 = (const float*)d_in[3];
  const float* g0 = (const float*)d_in[4],  *bt0 = (const float*)d_in[5];
  const float* w1 = (const float*)d_in[6],  *b1 = (const float*)d_in[7];
  const float* g1 = (const float*)d_in[8],  *bt1 = (const float*)d_in[9];
  const float* w2 = (const float*)d_in[10], *b2 = (const float*)d_in[11];
  const float* g2 = (const float*)d_in[12], *bt2 = (const float*)d_in[13];

  float* cents = (float*)d_out;                    // 8*2048*3
  float* outp  = cents + (size_t)NB * NS * 3;      // 8*2048*128

  int*   gidx  = (int*)d_ws;                       // 524288 ints (2 MB)
  float* stats = (float*)((char*)d_ws + (size_t)NROWS * sizeof(int)); // 4096 f32
  float* prm   = stats + 4096;                     // 512 f32

  fps_kernel<<<NB, 256, 0, stream>>>(xyz, cents);
  ballq_kernel<<<(NB*NS*64)/256, 256, 0, stream>>>(xyz, cents, gidx);
  zero_kernel<<<16, 256, 0, stream>>>(stats, 4096);

  chain_kernel<1><<<NROWS/128, 128, 0, stream>>>(xyz, feats, cents, gidx,
      w0, b0, w1, b1, w2, b2, prm, stats, outp);
  finalize_kernel<<<1, 128, 0, stream>>>(stats + 0, g0, bt0, prm + 0, prm + 64, 64);

  chain_kernel<2><<<NROWS/128, 128, 0, stream>>>(xyz, feats, cents, gidx,
      w0, b0, w1, b1, w2, b2, prm, stats, outp);
  finalize_kernel<<<1, 128, 0, stream>>>(stats + 1024, g1, bt1, prm + 128, prm + 192, 64);

  chain_kernel<3><<<NROWS/128, 128, 0, stream>>>(xyz, feats, cents, gidx,
      w0, b0, w1, b1, w2, b2, prm, stats, outp);
  finalize_kernel<<<1, 128, 0, stream>>>(stats + 2048, g2, bt2, prm + 256, prm + 384, 128);

  chain_kernel<4><<<NROWS/128, 128, 0, stream>>>(xyz, feats, cents, gidx,
      w0, b0, w1, b1, w2, b2, prm, stats, outp);
}

// Round 3
// 3838.600 us; speedup vs baseline: 1.4248x; 1.4248x over previous
//
#include <hip/hip_runtime.h>
#include <cstdint>
#include <cstddef>

#define NPTS 8192
#define NB 8
#define NS 2048
#define KG 32
#define NROWS (NB*NS*KG)   // 524288
#define NREP 32            // stats atomic replication

// Distance with NO fma contraction: bitwise-identical to numpy f32
// ((dx*dx + dy*dy) + dz*dz).
__device__ __forceinline__ float dist2_exact(float ax, float ay, float az,
                                             float bx, float by, float bz)
{
#pragma clang fp contract(off)
  float dx = ax - bx;
  float dy = ay - by;
  float dz = az - bz;
  return dx * dx + dy * dy + dz * dz;
}

// ======================== FPS ========================
// One block per batch, 512 threads x 16 pts in regs. Selection key is a bare
// u64 (dmin_bits<<32 | ~idx): max == argmax with first-index tiebreak.
// Winner coords come from a same-address LDS broadcast (coords staged once).
__launch_bounds__(512)
__global__ void fps_kernel(const float* __restrict__ xyz, float* __restrict__ cents)
{
  __shared__ float sx[NPTS], sy[NPTS], sz[NPTS];       // 96 KB
  __shared__ unsigned long long spk[2][8];

  const int b = blockIdx.x;
  const int t = threadIdx.x;
  const float* base = xyz + (size_t)b * NPTS * 3;

  float px[16], py[16], pz[16], dmin[16];
  unsigned int lo[16];
#pragma unroll
  for (int j = 0; j < 16; ++j) {
    int i = j * 512 + t;
    float x = base[3*i+0], y = base[3*i+1], z = base[3*i+2];
    px[j] = x; py[j] = y; pz[j] = z;
    dmin[j] = 1e10f;
    lo[j] = ~(unsigned)i;
    sx[i] = x; sy[i] = y; sz[i] = z;
  }

  float cx = base[0], cy = base[1], cz = base[2];
  if (t == 0) {
    float* c0 = cents + (size_t)b * NS * 3;
    c0[0] = cx; c0[1] = cy; c0[2] = cz;
  }
  __syncthreads();   // coords staged

  for (int it = 1; it < NS; ++it) {
    unsigned long long best = 0ull;
#pragma unroll
    for (int j = 0; j < 16; ++j) {
      float d = dist2_exact(px[j], py[j], pz[j], cx, cy, cz);
      float m = fminf(dmin[j], d);
      dmin[j] = m;
      unsigned long long p = ((unsigned long long)__float_as_uint(m) << 32)
                           | (unsigned long long)lo[j];
      best = (p > best) ? p : best;
    }
#pragma unroll
    for (int off = 32; off > 0; off >>= 1) {
      unsigned long long op = __shfl_xor(best, off, 64);
      best = (op > best) ? op : best;
    }
    const int pb = it & 1;     // double-buffered partials: one barrier/iter
    if ((t & 63) == 0) spk[pb][t >> 6] = best;
    __syncthreads();
    unsigned long long bb = spk[pb][0];
#pragma unroll
    for (int q = 1; q < 8; ++q) {
      unsigned long long oq = spk[pb][q];
      bb = (oq > bb) ? oq : bb;
    }
    const int win = (int)(~(unsigned)bb);
    cx = sx[win]; cy = sy[win]; cz = sz[win];   // same-address broadcast
    if (t == 0) {
      float* cp = cents + ((size_t)b * NS + it) * 3;
      cp[0] = cx; cp[1] = cy; cp[2] = cz;
    }
  }
}

// ======================== Ball query ========================
__launch_bounds__(256)
__global__ void ballq_kernel(const float* __restrict__ xyz,
                             const float* __restrict__ cents,
                             int* __restrict__ gidx)
{
  const int gid  = blockIdx.x * 256 + threadIdx.x;
  const int w    = gid >> 6;          // centroid id 0..16383
  const int lane = gid & 63;
  const int b    = w >> 11;
  const float* base = xyz + (size_t)b * NPTS * 3;
  const float cx = cents[3*w+0], cy = cents[3*w+1], cz = cents[3*w+2];
  const float R2 = (float)(0.2 * 0.2);
  int* out = gidx + (size_t)w * KG;

  int filled = 0, first = -1;
  for (int c = 0; c < NPTS/64; ++c) {
    int i = (c << 6) | lane;
    float d = dist2_exact(base[3*i+0], base[3*i+1], base[3*i+2], cx, cy, cz);
    bool inb = (d <= R2);
    unsigned long long mask = __ballot(inb);
    if (first < 0 && mask) first = (c << 6) + (__ffsll((long long)mask) - 1);
    int pre  = __popcll(mask & ((1ull << lane) - 1ull));
    int slot = filled + pre;
    if (inb && slot < KG) out[slot] = i;
    filled += __popcll(mask);
    if (filled >= KG) break;
  }
  if (filled < KG && lane < KG && lane >= filled) out[lane] = first;
}

// ======================== shuffle fold-reductions ========================
template<int H>
__device__ __forceinline__ void fold_sum_step(float* a, int lane) {
#pragma unroll
  for (int q = 0; q < H; ++q) {
    float keep = (lane & H) ? a[q + H] : a[q];
    float send = (lane & H) ? a[q] : a[q + H];
    a[q] = keep + __shfl_xor(send, H, 64);
  }
}

// Destroys a[16]. Returns: every lane holds full-wave (64-row) sum of
// channel (lane & 15).
__device__ __forceinline__ float fold_sum16(float* a, int lane) {
  fold_sum_step<8>(a, lane);
  fold_sum_step<4>(a, lane);
  fold_sum_step<2>(a, lane);
  fold_sum_step<1>(a, lane);
  float v = a[0];
  v += __shfl_xor(v, 16, 64);
  v += __shfl_xor(v, 32, 64);
  return v;
}

template<int H>
__device__ __forceinline__ void fold_max_step(float* a, int lane) {
#pragma unroll
  for (int q = 0; q < H; ++q) {
    float keep = (lane & H) ? a[q + H] : a[q];
    float send = (lane & H) ? a[q] : a[q + H];
    a[q] = fmaxf(keep, __shfl_xor(send, H, 64));
  }
}

// Destroys a[16]. Max across each 32-lane k-group; every lane holds
// channel (lane & 15)'s group-max.
__device__ __forceinline__ float fold_max16(float* a, int lane) {
  fold_max_step<8>(a, lane);
  fold_max_step<4>(a, lane);
  fold_max_step<2>(a, lane);
  fold_max_step<1>(a, lane);
  float v = a[0];
  v = fmaxf(v, __shfl_xor(v, 16, 64));
  return v;
}

// s1/s2 stats of 16 channels (o0 = dynamic channel base). Destroys y.
__device__ __forceinline__ void stats16(float* y, int lane, int o0,
                                        float* __restrict__ gs1,
                                        float* __restrict__ gs2)
{
  float sq[16];
#pragma unroll
  for (int q = 0; q < 16; ++q) sq[q] = y[q] * y[q];
  float s1 = fold_sum16(y, lane);
  float s2 = fold_sum16(sq, lane);
  if (lane < 16)       atomicAdd(&gs1[o0 + lane], s1);
  else if (lane < 32)  atomicAdd(&gs2[o0 + (lane & 15)], s2);
}

// ======================== MLP chain (no LDS, no barriers) ========================
// stats layout (floats): L0 s1 @0 (32x64), s2 @2048 | L1 @4096 | L2 @8192
// (s1 32x128, s2 @+4096). total 16384 floats.
// prm: a0@0 sh0@64 a1@128 sh1@192 a2@256 sh2@384.
template<int MODE>
__launch_bounds__(256, (MODE <= 2 ? 4 : 2))
__global__ void chain_kernel(const float* __restrict__ xyz,
                             const float* __restrict__ feats,
                             const float* __restrict__ cents,
                             const int* __restrict__ gidx,
                             const float* __restrict__ w0, const float* __restrict__ b0,
                             const float* __restrict__ w1, const float* __restrict__ b1,
                             const float* __restrict__ w2, const float* __restrict__ b2,
                             const float* __restrict__ prm,
                             float* __restrict__ stats,
                             float* __restrict__ outp)
{
  const int t    = threadIdx.x;
  const int lane = t & 63;
  const int r    = blockIdx.x * 256 + t;
  const int b    = r >> 16;
  const int cs   = r >> 5;
  const int i    = gidx[r];
  const int rep  = (blockIdx.x * 4 + (t >> 6)) & (NREP - 1);

  const float* pp = xyz + ((size_t)(b << 13) + i) * 3;
  const float* cc = cents + (size_t)cs * 3;
  const float* fb = feats + (((size_t)(b << 13) + i) << 6);

  // ---- dense0, streaming input chunks (acc[64] live, input never fully held)
  float acc[64];
  {
    float c0 = pp[0] - cc[0], c1 = pp[1] - cc[1], c2 = pp[2] - cc[2];
#pragma unroll
    for (int o = 0; o < 64; ++o)
      acc[o] = fmaf(w0[o*67+2], c2, fmaf(w0[o*67+1], c1, fmaf(w0[o*67+0], c0, b0[o])));
  }
  for (int c0 = 0; c0 < 64; c0 += 16) {
    float xc[16];
    const float4* f4 = (const float4*)(fb + c0);
    float4 v0 = f4[0], v1 = f4[1], v2 = f4[2], v3 = f4[3];
    xc[0]=v0.x; xc[1]=v0.y; xc[2]=v0.z; xc[3]=v0.w;
    xc[4]=v1.x; xc[5]=v1.y; xc[6]=v1.z; xc[7]=v1.w;
    xc[8]=v2.x; xc[9]=v2.y; xc[10]=v2.z; xc[11]=v2.w;
    xc[12]=v3.x; xc[13]=v3.y; xc[14]=v3.z; xc[15]=v3.w;
#pragma unroll
    for (int o = 0; o < 64; ++o) {
      float a = acc[o];
#pragma unroll
      for (int ci = 0; ci < 16; ++ci)      // ci innermost: s_load_dwordx4 batching
        a = fmaf(w0[o*67 + 3 + c0 + ci], xc[ci], a);
      acc[o] = a;
    }
  }

  if (MODE == 1) {
#pragma unroll
    for (int o0 = 0; o0 < 64; o0 += 16) {
      float y[16];
#pragma unroll
      for (int q = 0; q < 16; ++q) y[q] = acc[o0 + q];
      stats16(y, lane, o0, stats + (size_t)rep*64, stats + 2048 + (size_t)rep*64);
    }
    return;
  }

  // ---- norm0 + relu in place
#pragma unroll
  for (int o = 0; o < 64; ++o)
    acc[o] = fmaxf(fmaf(prm[o], acc[o], prm[64 + o]), 0.f);

  if (MODE == 2) {
    for (int o0 = 0; o0 < 64; o0 += 16) {
      float y[16];
#pragma unroll
      for (int k = 0; k < 16; ++k) {
        float a = b1[o0 + k];
#pragma unroll
        for (int c = 0; c < 64; ++c)
          a = fmaf(w1[(o0 + k)*64 + c], acc[c], a);
        y[k] = a;
      }
      stats16(y, lane, o0, stats + 4096 + (size_t)rep*64, stats + 4096 + 2048 + (size_t)rep*64);
    }
    return;
  }

  // ---- dense1 full (static outputs), then norm1+relu in place
  float y1[64];
#pragma unroll
  for (int o = 0; o < 64; ++o) {
    float a = b1[o];
#pragma unroll
    for (int c = 0; c < 64; ++c)
      a = fmaf(w1[o*64 + c], acc[c], a);
    y1[o] = a;
  }
#pragma unroll
  for (int o = 0; o < 64; ++o)
    y1[o] = fmaxf(fmaf(prm[128 + o], y1[o], prm[192 + o]), 0.f);

  if (MODE == 3) {
    for (int o0 = 0; o0 < 128; o0 += 16) {
      float y[16];
#pragma unroll
      for (int k = 0; k < 16; ++k) {
        float a = b2[o0 + k];
#pragma unroll
        for (int c = 0; c < 64; ++c)
          a = fmaf(w2[(o0 + k)*64 + c], y1[c], a);
        y[k] = a;
      }
      stats16(y, lane, o0, stats + 8192 + (size_t)rep*128, stats + 8192 + 4096 + (size_t)rep*128);
    }
    return;
  }

  // ---- MODE 4: dense2 chunks + norm2 + relu + k-group max + store
  for (int o0 = 0; o0 < 128; o0 += 16) {
    float y[16];
#pragma unroll
    for (int k = 0; k < 16; ++k) {
      float a = b2[o0 + k];
#pragma unroll
      for (int c = 0; c < 64; ++c)
        a = fmaf(w2[(o0 + k)*64 + c], y1[c], a);
      y[k] = a;
    }
#pragma unroll
    for (int k = 0; k < 16; ++k)
      y[k] = fmaxf(fmaf(prm[256 + o0 + k], y[k], prm[384 + o0 + k]), 0.f);
    float m = fold_max16(y, lane);
    if (!(lane & 16))
      outp[(size_t)cs * 128 + o0 + (lane & 15)] = m;
  }
}

__global__ void finalize_kernel(const float* __restrict__ stats,
                                const float* __restrict__ g,
                                const float* __restrict__ beta,
                                float* __restrict__ pa, float* __restrict__ psh, int C)
{
  int c = threadIdx.x;
  if (c >= C) return;
  float s1 = 0.f, s2 = 0.f;
  for (int rr = 0; rr < NREP; ++rr) { s1 += stats[rr*C + c]; s2 += stats[NREP*C + rr*C + c]; }
  const float invn = 1.0f / (float)NROWS;
  float mean = s1 * invn;
  float var  = s2 * invn - mean * mean;
  float rs   = 1.0f / sqrtf(var + 1e-5f);
  float a    = g[c] * rs;
  pa[c]  = a;
  psh[c] = fmaf(-mean, a, beta[c]);
}

__global__ void zero_kernel(float* __restrict__ p, int n)
{
  int i = blockIdx.x * 256 + threadIdx.x;
  if (i < n) p[i] = 0.f;
}

// ======================== launch ========================
extern "C" void kernel_launch(void* const* d_in, const int* in_sizes, int n_in,
                              void* d_out, int out_size, void* d_ws, size_t ws_size,
                              hipStream_t stream)
{
  (void)in_sizes; (void)n_in; (void)out_size; (void)ws_size;
  const float* xyz   = (const float*)d_in[0];
  const float* feats = (const float*)d_in[1];
  const float* w0 = (const float*)d_in[2],  *b0 = (const float*)d_in[3];
  const float* g0 = (const float*)d_in[4],  *bt0 = (const float*)d_in[5];
  const float* w1 = (const float*)d_in[6],  *b1 = (const float*)d_in[7];
  const float* g1 = (const float*)d_in[8],  *bt1 = (const float*)d_in[9];
  const float* w2 = (const float*)d_in[10], *b2 = (const float*)d_in[11];
  const float* g2 = (const float*)d_in[12], *bt2 = (const float*)d_in[13];

  float* cents = (float*)d_out;                    // 8*2048*3
  float* outp  = cents + (size_t)NB * NS * 3;      // 8*2048*128

  int*   gidx  = (int*)d_ws;                       // 524288 ints (2 MB)
  float* stats = (float*)((char*)d_ws + (size_t)NROWS * sizeof(int)); // 16384 f32
  float* prm   = stats + 16384;                    // 512 f32

  fps_kernel<<<NB, 512, 0, stream>>>(xyz, cents);
  ballq_kernel<<<(NB*NS*64)/256, 256, 0, stream>>>(xyz, cents, gidx);
  zero_kernel<<<64, 256, 0, stream>>>(stats, 16384);

  chain_kernel<1><<<NROWS/256, 256, 0, stream>>>(xyz, feats, cents, gidx,
      w0, b0, w1, b1, w2, b2, prm, stats, outp);
  finalize_kernel<<<1, 128, 0, stream>>>(stats + 0, g0, bt0, prm + 0, prm + 64, 64);

  chain_kernel<2><<<NROWS/256, 256, 0, stream>>>(xyz, feats, cents, gidx,
      w0, b0, w1, b1, w2, b2, prm, stats, outp);
  finalize_kernel<<<1, 128, 0, stream>>>(stats + 4096, g1, bt1, prm + 128, prm + 192, 64);

  chain_kernel<3><<<NROWS/256, 256, 0, stream>>>(xyz, feats, cents, gidx,
      w0, b0, w1, b1, w2, b2, prm, stats, outp);
  finalize_kernel<<<1, 128, 0, stream>>>(stats + 8192, g2, bt2, prm + 256, prm + 384, 128);

  chain_kernel<4><<<NROWS/256, 256, 0, stream>>>(xyz, feats, cents, gidx,
      w0, b0, w1, b1, w2, b2, prm, stats, outp);
}